// Round 1
// baseline (95.496 us; speedup 1.0000x reference)
//
#include <hip/hip_runtime.h>

#define N_SAMPLES   8192
#define CODE_LEN    128
#define NUM_CLASSES 1000
#define ABSENT_PEN  4096u

// ws layout:
//   [0]      double   bce_acc
//   [8]      unsigned sigma_acc
//   [64]     unsigned penalty[1024]        (4 KB)
//   [8192]   uint4    cw_packed[1000]      (16000 B)
//   [32768]  uint4    pred_packed[8192]    (128 KB)

__global__ __launch_bounds__(1024) void init_kernel(unsigned* __restrict__ penalty,
                                                    double* __restrict__ bce_acc,
                                                    unsigned* __restrict__ sigma_acc) {
    int t = threadIdx.x;                 // one block of 1024
    penalty[t] = ABSENT_PEN;
    if (t == 0) { *bce_acc = 0.0; *sigma_acc = 0u; }
}

// Blocks [0,250): pack codewords (4 classes/block via 4 waves).
// Blocks [250,2298): 4 samples/block — BCE wave-sum, pred bit-pack, presence mark.
__global__ __launch_bounds__(256) void pack_bce_kernel(
        const float* __restrict__ output, const float* __restrict__ codewords,
        const int* __restrict__ target,
        unsigned* __restrict__ penalty, uint4* __restrict__ cw_packed,
        uint4* __restrict__ pred_packed, double* __restrict__ bce_acc) {
    __shared__ float wsum[4];
    const int b   = blockIdx.x;
    const int tid = threadIdx.x;
    const int w   = tid >> 6;     // wave in block
    const int l   = tid & 63;     // lane

    if (b < 250) {
        const int c = b * 4 + w;  // < 1000 always
        float v0 = codewords[c * CODE_LEN + l];
        float v1 = codewords[c * CODE_LEN + 64 + l];
        unsigned long long b0 = __ballot(v0 > 0.5f);
        unsigned long long b1 = __ballot(v1 > 0.5f);
        if (l == 0) {
            cw_packed[c] = make_uint4((unsigned)b0, (unsigned)(b0 >> 32),
                                      (unsigned)b1, (unsigned)(b1 >> 32));
        }
    } else {
        const int i = (b - 250) * 4 + w;          // sample index, < 8192
        const int t = target[i];
        float o0 = output[i * CODE_LEN + l];
        float o1 = output[i * CODE_LEN + 64 + l];
        float c0 = codewords[t * CODE_LEN + l];
        float c1 = codewords[t * CODE_LEN + 64 + l];
        // bce = cw ? -log(o) : -log1p(-o)
        float bce = (c0 > 0.5f ? -logf(o0) : -log1pf(-o0))
                  + (c1 > 0.5f ? -logf(o1) : -log1pf(-o1));
        unsigned long long p0 = __ballot(o0 > 0.5f);
        unsigned long long p1 = __ballot(o1 > 0.5f);
        // wave-reduce the 64 partial BCE sums
        #pragma unroll
        for (int m = 1; m <= 32; m <<= 1) bce += __shfl_xor(bce, m);
        if (l == 0) {
            pred_packed[i] = make_uint4((unsigned)p0, (unsigned)(p0 >> 32),
                                        (unsigned)p1, (unsigned)(p1 >> 32));
            penalty[t] = 0u;              // idempotent presence mark
            wsum[w] = bce;
        }
        __syncthreads();
        if (tid == 0) {
            atomicAdd(bce_acc, (double)(wsum[0] + wsum[1] + wsum[2] + wsum[3]));
        }
    }
}

// 32 samples/block, 8 threads/sample, classes staged in LDS.
__global__ __launch_bounds__(256) void sigma_kernel(
        const uint4* __restrict__ cw_packed, const unsigned* __restrict__ penalty,
        const uint4* __restrict__ pred_packed, unsigned* __restrict__ sigma_acc) {
    __shared__ uint4    lcw[NUM_CLASSES];
    __shared__ unsigned lpen[NUM_CLASSES];
    __shared__ unsigned bsum[4];
    const int tid = threadIdx.x;
    for (int c = tid; c < NUM_CLASSES; c += 256) {
        lcw[c]  = cw_packed[c];
        lpen[c] = penalty[c];
    }
    __syncthreads();

    const int i  = blockIdx.x * 32 + (tid >> 3);  // sample
    const int cl = tid & 7;                       // class lane within sample group
    const uint4 p = pred_packed[i];

    unsigned best = 0xFFFFFFFFu;
    for (int c = cl; c < NUM_CLASSES; c += 8) {
        uint4 cw = lcw[c];
        unsigned pop = __popc(p.x ^ cw.x) + __popc(p.y ^ cw.y)
                     + __popc(p.z ^ cw.z) + __popc(p.w ^ cw.w) + lpen[c];
        best = min(best, pop);
    }
    // min across the 8 threads of this sample (consecutive lanes)
    #pragma unroll
    for (int m = 1; m <= 4; m <<= 1)
        best = min(best, (unsigned)__shfl_xor((int)best, m));
    // sum the 8 per-sample minima of this wave (all 8 lanes/group hold the min)
    unsigned s = best;
    #pragma unroll
    for (int m = 8; m <= 32; m <<= 1) s += (unsigned)__shfl_xor((int)s, m);
    if ((tid & 63) == 0) bsum[tid >> 6] = s;
    __syncthreads();
    if (tid == 0) atomicAdd(sigma_acc, bsum[0] + bsum[1] + bsum[2] + bsum[3]);
}

__global__ void finalize_kernel(const double* __restrict__ bce_acc,
                                const unsigned* __restrict__ sigma_acc,
                                float* __restrict__ out) {
    out[0] = (float)(*bce_acc / (double)(N_SAMPLES * CODE_LEN)
                   + (double)(*sigma_acc) / (double)N_SAMPLES);
}

extern "C" void kernel_launch(void* const* d_in, const int* in_sizes, int n_in,
                              void* d_out, int out_size, void* d_ws, size_t ws_size,
                              hipStream_t stream) {
    const float* output    = (const float*)d_in[0];   // [8192,128] f32
    const float* codewords = (const float*)d_in[1];   // [1000,128] f32
    const int*   target    = (const int*)d_in[2];     // [8192] int32
    float*       out       = (float*)d_out;

    char* ws = (char*)d_ws;
    double*   bce_acc     = (double*)(ws + 0);
    unsigned* sigma_acc   = (unsigned*)(ws + 8);
    unsigned* penalty     = (unsigned*)(ws + 64);
    uint4*    cw_packed   = (uint4*)(ws + 8192);
    uint4*    pred_packed = (uint4*)(ws + 32768);

    init_kernel<<<1, 1024, 0, stream>>>(penalty, bce_acc, sigma_acc);
    pack_bce_kernel<<<250 + N_SAMPLES / 4, 256, 0, stream>>>(
        output, codewords, target, penalty, cw_packed, pred_packed, bce_acc);
    sigma_kernel<<<N_SAMPLES / 32, 256, 0, stream>>>(
        cw_packed, penalty, pred_packed, sigma_acc);
    finalize_kernel<<<1, 1, 0, stream>>>(bce_acc, sigma_acc, out);
}

// Round 2
// 79.126 us; speedup vs baseline: 1.2069x; 1.2069x over previous
//
#include <hip/hip_runtime.h>

#define N_SAMPLES   8192
#define CODE_LEN    128
#define NUM_CLASSES 1000

// ws layout:
//   [0]      unsigned sigma_acc
//   [4]      unsigned done_counter
//   [64]     float    bce_part[2048]      (8 KB)
//   [8320]   uint4    cw_packed[1000]     (16000 B)
//   [24576]  uint4    pred_packed[8192]   (128 KB)

// K1 — blocks [0,250): pack 4 codewords/block (one per wave).
//      blocks [250,2298): 4 samples/block — BCE wave-sum + pred bit-pack.
//      block 0 thread 0 additionally inits the K2 accumulators (stream order
//      guarantees K1 completes before K2 starts).
__global__ __launch_bounds__(256) void pack_bce_kernel(
        const float* __restrict__ output, const float* __restrict__ codewords,
        const int* __restrict__ target,
        uint4* __restrict__ cw_packed, uint4* __restrict__ pred_packed,
        float* __restrict__ bce_part,
        unsigned* __restrict__ sigma_acc, unsigned* __restrict__ counter) {
    __shared__ float wsum[4];
    const int b   = blockIdx.x;
    const int tid = threadIdx.x;
    const int w   = tid >> 6;     // wave in block
    const int l   = tid & 63;     // lane

    if (b == 0 && tid == 0) { *sigma_acc = 0u; *counter = 0u; }

    if (b < 250) {
        const int c = b * 4 + w;  // < 1000
        float v0 = codewords[c * CODE_LEN + l];
        float v1 = codewords[c * CODE_LEN + 64 + l];
        unsigned long long b0 = __ballot(v0 > 0.5f);
        unsigned long long b1 = __ballot(v1 > 0.5f);
        if (l == 0) {
            cw_packed[c] = make_uint4((unsigned)b0, (unsigned)(b0 >> 32),
                                      (unsigned)b1, (unsigned)(b1 >> 32));
        }
    } else {
        const int i = (b - 250) * 4 + w;          // sample index < 8192
        const int t = target[i];
        float o0 = output[i * CODE_LEN + l];
        float o1 = output[i * CODE_LEN + 64 + l];
        float c0 = codewords[t * CODE_LEN + l];
        float c1 = codewords[t * CODE_LEN + 64 + l];
        float bce = (c0 > 0.5f ? -logf(o0) : -log1pf(-o0))
                  + (c1 > 0.5f ? -logf(o1) : -log1pf(-o1));
        unsigned long long p0 = __ballot(o0 > 0.5f);
        unsigned long long p1 = __ballot(o1 > 0.5f);
        #pragma unroll
        for (int m = 1; m <= 32; m <<= 1) bce += __shfl_xor(bce, m);
        if (l == 0) {
            pred_packed[i] = make_uint4((unsigned)p0, (unsigned)(p0 >> 32),
                                        (unsigned)p1, (unsigned)(p1 >> 32));
            wsum[w] = bce;
        }
        __syncthreads();
        if (tid == 0) {
            bce_part[b - 250] = wsum[0] + wsum[1] + wsum[2] + wsum[3];
        }
    }
}

// K2 — 256 blocks, 32 samples/block, 8 threads/sample.
// Presence rebuilt per-block in LDS (benign-race byte writes), so no global
// init is needed. Last block to finish sums the BCE partials and writes out.
__global__ __launch_bounds__(256) void sigma_kernel(
        const uint4* __restrict__ cw_packed, const uint4* __restrict__ pred_packed,
        const int* __restrict__ target, const float* __restrict__ bce_part,
        unsigned* __restrict__ sigma_acc, unsigned* __restrict__ counter,
        float* __restrict__ out) {
    __shared__ uint4         lcw[NUM_CLASSES];
    __shared__ unsigned char lpen[1024];
    __shared__ unsigned      bsum[4];
    __shared__ double        dsum[4];
    __shared__ int           is_last;
    const int tid = threadIdx.x;

    // zero the presence bytes (256 threads x 4 B = 1024 B)
    ((unsigned*)lpen)[tid] = 0u;
    __syncthreads();
    // stage codewords + mark presence (same-value WAW races are benign)
    for (int c = tid; c < NUM_CLASSES; c += 256) lcw[c] = cw_packed[c];
    for (int k = tid; k < N_SAMPLES; k += 256) lpen[target[k]] = 1;
    __syncthreads();

    const int i  = blockIdx.x * 32 + (tid >> 3);  // sample
    const int cl = tid & 7;
    const uint4 p = pred_packed[i];

    unsigned best = 0xFFFFFFFFu;
    for (int c = cl; c < NUM_CLASSES; c += 8) {
        uint4 cw = lcw[c];
        unsigned pop = __popc(p.x ^ cw.x) + __popc(p.y ^ cw.y)
                     + __popc(p.z ^ cw.z) + __popc(p.w ^ cw.w);
        pop += ((unsigned)(lpen[c] == 0)) << 12;   // absent-class penalty
        best = min(best, pop);
    }
    #pragma unroll
    for (int m = 1; m <= 4; m <<= 1)
        best = min(best, (unsigned)__shfl_xor((int)best, m));
    unsigned s = best;
    #pragma unroll
    for (int m = 8; m <= 32; m <<= 1) s += (unsigned)__shfl_xor((int)s, m);
    if ((tid & 63) == 0) bsum[tid >> 6] = s;
    __syncthreads();

    if (tid == 0) {
        atomicAdd(sigma_acc, bsum[0] + bsum[1] + bsum[2] + bsum[3]);
        __threadfence();
        unsigned old = atomicAdd(counter, 1u);
        is_last = (old == (unsigned)(gridDim.x - 1)) ? 1 : 0;
    }
    __syncthreads();

    if (is_last) {
        // final reduction: 2048 BCE partials (written by K1) + sigma_acc
        double acc = 0.0;
        for (int k = tid; k < N_SAMPLES / 4; k += 256) acc += (double)bce_part[k];
        #pragma unroll
        for (int m = 1; m <= 32; m <<= 1) acc += __shfl_xor(acc, m);
        if ((tid & 63) == 0) dsum[tid >> 6] = acc;
        __syncthreads();
        if (tid == 0) {
            __threadfence();
            unsigned sig = atomicAdd(sigma_acc, 0u);   // L1-bypassing read
            double bce_total = dsum[0] + dsum[1] + dsum[2] + dsum[3];
            out[0] = (float)(bce_total / (double)(N_SAMPLES * CODE_LEN)
                           + (double)sig / (double)N_SAMPLES);
        }
    }
}

extern "C" void kernel_launch(void* const* d_in, const int* in_sizes, int n_in,
                              void* d_out, int out_size, void* d_ws, size_t ws_size,
                              hipStream_t stream) {
    const float* output    = (const float*)d_in[0];   // [8192,128] f32
    const float* codewords = (const float*)d_in[1];   // [1000,128] f32
    const int*   target    = (const int*)d_in[2];     // [8192] int32
    float*       out       = (float*)d_out;

    char* ws = (char*)d_ws;
    unsigned* sigma_acc   = (unsigned*)(ws + 0);
    unsigned* counter     = (unsigned*)(ws + 4);
    float*    bce_part    = (float*)(ws + 64);
    uint4*    cw_packed   = (uint4*)(ws + 8320);
    uint4*    pred_packed = (uint4*)(ws + 24576);

    pack_bce_kernel<<<250 + N_SAMPLES / 4, 256, 0, stream>>>(
        output, codewords, target, cw_packed, pred_packed, bce_part,
        sigma_acc, counter);
    sigma_kernel<<<N_SAMPLES / 32, 256, 0, stream>>>(
        cw_packed, pred_packed, target, bce_part, sigma_acc, counter, out);
}